// Round 5
// baseline (488.605 us; speedup 1.0000x reference)
//
#include <hip/hip_runtime.h>

#define T_STEPS 20
#define BATCH   65536
#define HIDN    64
#define GATES   256
#define CHUNKS  2        // 16-row chunks per persistent WG
#define HSTR    72       // hl row stride (bf16 elems)

typedef __bf16 bf16x8 __attribute__((ext_vector_type(8)));
typedef float  f32x4  __attribute__((ext_vector_type(4)));
typedef float  f32x2  __attribute__((ext_vector_type(2)));

#if __has_builtin(__builtin_amdgcn_exp2f)
#define EXP2F(x) __builtin_amdgcn_exp2f(x)
#else
#define EXP2F(x) exp2f(x)
#endif
#if __has_builtin(__builtin_amdgcn_rcpf)
#define RCPF(x) __builtin_amdgcn_rcpf(x)
#else
#define RCPF(x) (1.0f / (x))
#endif

__device__ __forceinline__ float sigmoid_f(float x) {
    return RCPF(1.0f + EXP2F(x * -1.4426950408889634f));
}
__device__ __forceinline__ float tanh_f(float x) {
    return 1.0f - 2.0f * RCPF(1.0f + EXP2F(x * 2.8853900817779268f));
}

// WG = 4 waves = 16 batch rows. Wave jtw owns hidden slice [16*jtw, 16*jtw+16):
// it computes gate tiles {jtw, 4+jtw, 8+jtw, 12+jtw} (i,f,g,o for its slice),
// holding the 8 needed W_hh B-fragments in REGISTERS (32 VGPR).
// Steady-state LDS = 2x ds_read_b128 + 4x ds_write_b16 per wave/step,
// double-buffered h tile, one barrier per step.
// 2048 WGs = 8 WGs/CU = 32 waves/CU: barrier/latency stalls hidden by TLP.
__global__ __launch_bounds__(256, 8)
void Encoder_6949257085628_kernel(const float* __restrict__ obs,
                                  const float* __restrict__ W_emb,
                                  const float* __restrict__ b_emb,
                                  const float* __restrict__ W_ih,
                                  const float* __restrict__ W_hh,
                                  const float* __restrict__ b_ih,
                                  const float* __restrict__ b_hh,
                                  float* __restrict__ out) {
    __shared__ float wcbc[GATES * 3];                    // 3 KB
    __shared__ __align__(16) __bf16 hlb[2][16 * HSTR];   // 2 x 2.25 KB, dbuf

    const int tid  = threadIdx.x;
    const int jtw  = tid >> 6;       // wave index = hidden-quarter
    const int lane = tid & 63;
    const int q    = lane >> 4;      // 0..3
    const int c16  = lane & 15;

    // ---- fold embedding into gate map: Wc (256x2), bc (256) ----
    {
        int g = tid;  // exactly 256 threads
        float a0 = 0.f, a1 = 0.f, ab = 0.f;
        for (int e = 0; e < 64; ++e) {
            float wie = W_ih[g * 64 + e];
            a0 = fmaf(wie, W_emb[e * 2 + 0], a0);
            a1 = fmaf(wie, W_emb[e * 2 + 1], a1);
            ab = fmaf(wie, b_emb[e], ab);
        }
        wcbc[g * 3 + 0] = a0;
        wcbc[g * 3 + 1] = a1;
        wcbc[g * 3 + 2] = ab + b_ih[g] + b_hh[g];
    }

    // ---- load this wave's 8 W_hh B-fragments into registers ----
    // B[k][n] = W_hh[n][k]; frag (tile,ks): lane holds n = tile*16+c16,
    // k = ks*32 + q*8 + j  (8 consecutive fp32 of one W_hh row).
    bf16x8 bfr[4][2];
    #pragma unroll
    for (int f = 0; f < 4; ++f) {
        const int rowW = (f * 4 + jtw) * 16 + c16;   // gate column
        #pragma unroll
        for (int ks = 0; ks < 2; ++ks) {
            const float* p = W_hh + rowW * 64 + ks * 32 + q * 8;
            f32x4 lo = *(const f32x4*)p;
            f32x4 hi = *(const f32x4*)(p + 4);
            bf16x8 b;
            b[0] = (__bf16)lo[0]; b[1] = (__bf16)lo[1];
            b[2] = (__bf16)lo[2]; b[3] = (__bf16)lo[3];
            b[4] = (__bf16)hi[0]; b[5] = (__bf16)hi[1];
            b[6] = (__bf16)hi[2]; b[7] = (__bf16)hi[3];
            bfr[f][ks] = b;
        }
    }
    __syncthreads();   // wcbc staged

    // per-lane x->gate constants for this wave's 4 gate columns
    float w0v[4], w1v[4], bcv[4];
    #pragma unroll
    for (int f = 0; f < 4; ++f) {
        int col = (f * 4 + jtw) * 16 + c16;
        w0v[f] = wcbc[col * 3 + 0];
        w1v[f] = wcbc[col * 3 + 1];
        bcv[f] = wcbc[col * 3 + 2];
    }

    const int wgBase = blockIdx.x * (16 * CHUNKS);
    const int hOff   = jtw * 16 + c16;          // this lane's hidden index

    #pragma unroll 1
    for (int c = 0; c < CHUNKS; ++c) {
        const int rbw = wgBase + c * 16;

        float cst[4];
        #pragma unroll
        for (int r = 0; r < 4; ++r) cst[r] = 0.f;

        f32x2 xc[4];
        #pragma unroll
        for (int r = 0; r < 4; ++r)
            xc[r] = *(const f32x2*)&obs[(size_t)(rbw + q * 4 + r) * 2];

        #pragma unroll 1
        for (int t = 0; t < T_STEPS; ++t) {
            // prefetch next step's x
            f32x2 xn[4];
            {
                int tn = (t + 1 < T_STEPS) ? t + 1 : t;
                const float* ob = obs + (size_t)tn * (BATCH * 2);
                #pragma unroll
                for (int r = 0; r < 4; ++r)
                    xn[r] = *(const f32x2*)&ob[(size_t)(rbw + q * 4 + r) * 2];
            }

            // gate init: x-contribution + bias (fp32)
            f32x4 acc[4];
            #pragma unroll
            for (int f = 0; f < 4; ++f)
                #pragma unroll
                for (int r = 0; r < 4; ++r)
                    acc[f][r] = fmaf(xc[r][1], w1v[f],
                               fmaf(xc[r][0], w0v[f], bcv[f]));

            // recurrent GEMM for this wave's 4 gate tiles (h==0 at t=0)
            if (t > 0) {
                const __bf16* hp = hlb[(t & 1) ^ 1];
                bf16x8 a0 = *(const bf16x8*)&hp[c16 * HSTR + q * 8];
                bf16x8 a1 = *(const bf16x8*)&hp[c16 * HSTR + 32 + q * 8];
                #pragma unroll
                for (int f = 0; f < 4; ++f) {
                    acc[f] = __builtin_amdgcn_mfma_f32_16x16x32_bf16(a0, bfr[f][0], acc[f], 0, 0, 0);
                    acc[f] = __builtin_amdgcn_mfma_f32_16x16x32_bf16(a1, bfr[f][1], acc[f], 0, 0, 0);
                }
            }

            // activations + state update for (rows q*4+r, hidden hOff)
            __bf16* hw = hlb[t & 1];
            #pragma unroll
            for (int r = 0; r < 4; ++r) {
                float ig = sigmoid_f(acc[0][r]);
                float fg = sigmoid_f(acc[1][r]);
                float gg = tanh_f(acc[2][r]);
                float og = sigmoid_f(acc[3][r]);
                float cc = fmaf(fg, cst[r], ig * gg);
                cst[r] = cc;
                float h = og * tanh_f(cc);
                if (t < T_STEPS - 1) {
                    hw[(q * 4 + r) * HSTR + hOff] = (__bf16)h;
                } else {
                    out[(size_t)(rbw + q * 4 + r) * HIDN + hOff] = h;
                }
            }

            __syncthreads();  // h quarters exchanged; also guards chunk reuse

            #pragma unroll
            for (int r = 0; r < 4; ++r) xc[r] = xn[r];
        }
    }
}

extern "C" void kernel_launch(void* const* d_in, const int* in_sizes, int n_in,
                              void* d_out, int out_size, void* d_ws, size_t ws_size,
                              hipStream_t stream) {
    const float* obs   = (const float*)d_in[0];
    const float* W_emb = (const float*)d_in[1];
    const float* b_emb = (const float*)d_in[2];
    const float* W_ih  = (const float*)d_in[3];
    const float* W_hh  = (const float*)d_in[4];
    const float* b_ih  = (const float*)d_in[5];
    const float* b_hh  = (const float*)d_in[6];
    float* out = (float*)d_out;

    dim3 grid(BATCH / (16 * CHUNKS));  // 2048 WGs = 8 per CU
    dim3 block(256);
    Encoder_6949257085628_kernel<<<grid, block, 0, stream>>>(
        obs, W_emb, b_emb, W_ih, W_hh, b_ih, b_hh, out);
}

// Round 6
// 135.897 us; speedup vs baseline: 3.5954x; 3.5954x over previous
//
#include <hip/hip_runtime.h>

#define T_STEPS 20
#define BATCH   65536
#define HIDN    64
#define GATES   256
#define CHUNKS  2        // 16-row chunks per persistent WG -> 2048 WGs = 8/CU
#define HSTR    72       // hl row stride (bf16 elems)

typedef __bf16 bf16x8 __attribute__((ext_vector_type(8)));
typedef float  f32x4  __attribute__((ext_vector_type(4)));
typedef float  f32x2  __attribute__((ext_vector_type(2)));

#if __has_builtin(__builtin_amdgcn_exp2f)
#define EXP2F(x) __builtin_amdgcn_exp2f(x)
#else
#define EXP2F(x) exp2f(x)
#endif
#if __has_builtin(__builtin_amdgcn_rcpf)
#define RCPF(x) __builtin_amdgcn_rcpf(x)
#else
#define RCPF(x) (1.0f / (x))
#endif

__device__ __forceinline__ float sigmoid_f(float x) {
    return RCPF(1.0f + EXP2F(x * -1.4426950408889634f));
}
__device__ __forceinline__ float tanh_f(float x) {
    return 1.0f - 2.0f * RCPF(1.0f + EXP2F(x * 2.8853900817779268f));
}

// WG = 4 waves = 16 batch rows. Wave jtw owns hidden slice [16*jtw, 16*jtw+16):
// it computes gate tiles {jtw, 4+jtw, 8+jtw, 12+jtw} (i,f,g,o for its slice),
// holding the 8 needed W_hh B-fragments in REGISTERS (32 VGPR).
// Steady-state LDS = 2x ds_read_b128 + 4x ds_write_b16 per wave/step,
// double-buffered h tile, one barrier per step.
//
// __launch_bounds__(256,4): R5 proved min-waves=8 makes the allocator clamp
// to 32 VGPR and spill (1.5 GB scratch traffic). With min-waves=4 the kernel
// compiles to 60 VGPR, which ALREADY permits 8 waves/SIMD at runtime —
// occupancy is then set by the grid: 2048 WGs = 8 WGs/CU.
__global__ __launch_bounds__(256, 4)
void Encoder_6949257085628_kernel(const float* __restrict__ obs,
                                  const float* __restrict__ W_emb,
                                  const float* __restrict__ b_emb,
                                  const float* __restrict__ W_ih,
                                  const float* __restrict__ W_hh,
                                  const float* __restrict__ b_ih,
                                  const float* __restrict__ b_hh,
                                  float* __restrict__ out) {
    __shared__ float wcbc[GATES * 3];                    // 3 KB
    __shared__ __align__(16) __bf16 hlb[2][16 * HSTR];   // 2 x 2.25 KB, dbuf

    const int tid  = threadIdx.x;
    const int jtw  = tid >> 6;       // wave index = hidden-quarter
    const int lane = tid & 63;
    const int q    = lane >> 4;      // 0..3
    const int c16  = lane & 15;

    // ---- fold embedding into gate map: Wc (256x2), bc (256) ----
    {
        int g = tid;  // exactly 256 threads
        float a0 = 0.f, a1 = 0.f, ab = 0.f;
        for (int e = 0; e < 64; ++e) {
            float wie = W_ih[g * 64 + e];
            a0 = fmaf(wie, W_emb[e * 2 + 0], a0);
            a1 = fmaf(wie, W_emb[e * 2 + 1], a1);
            ab = fmaf(wie, b_emb[e], ab);
        }
        wcbc[g * 3 + 0] = a0;
        wcbc[g * 3 + 1] = a1;
        wcbc[g * 3 + 2] = ab + b_ih[g] + b_hh[g];
    }

    // ---- load this wave's 8 W_hh B-fragments into registers ----
    // B[k][n] = W_hh[n][k]; frag (tile,ks): lane holds n = tile*16+c16,
    // k = ks*32 + q*8 + j  (8 consecutive fp32 of one W_hh row).
    bf16x8 bfr[4][2];
    #pragma unroll
    for (int f = 0; f < 4; ++f) {
        const int rowW = (f * 4 + jtw) * 16 + c16;   // gate column
        #pragma unroll
        for (int ks = 0; ks < 2; ++ks) {
            const float* p = W_hh + rowW * 64 + ks * 32 + q * 8;
            f32x4 lo = *(const f32x4*)p;
            f32x4 hi = *(const f32x4*)(p + 4);
            bf16x8 b;
            b[0] = (__bf16)lo[0]; b[1] = (__bf16)lo[1];
            b[2] = (__bf16)lo[2]; b[3] = (__bf16)lo[3];
            b[4] = (__bf16)hi[0]; b[5] = (__bf16)hi[1];
            b[6] = (__bf16)hi[2]; b[7] = (__bf16)hi[3];
            bfr[f][ks] = b;
        }
    }
    __syncthreads();   // wcbc staged

    // per-lane x->gate constants for this wave's 4 gate columns
    float w0v[4], w1v[4], bcv[4];
    #pragma unroll
    for (int f = 0; f < 4; ++f) {
        int col = (f * 4 + jtw) * 16 + c16;
        w0v[f] = wcbc[col * 3 + 0];
        w1v[f] = wcbc[col * 3 + 1];
        bcv[f] = wcbc[col * 3 + 2];
    }

    const int wgBase = blockIdx.x * (16 * CHUNKS);
    const int hOff   = jtw * 16 + c16;          // this lane's hidden index

    #pragma unroll 1
    for (int c = 0; c < CHUNKS; ++c) {
        const int rbw = wgBase + c * 16;

        float cst[4];
        #pragma unroll
        for (int r = 0; r < 4; ++r) cst[r] = 0.f;

        f32x2 xc[4];
        #pragma unroll
        for (int r = 0; r < 4; ++r)
            xc[r] = *(const f32x2*)&obs[(size_t)(rbw + q * 4 + r) * 2];

        #pragma unroll 1
        for (int t = 0; t < T_STEPS; ++t) {
            // prefetch next step's x
            f32x2 xn[4];
            {
                int tn = (t + 1 < T_STEPS) ? t + 1 : t;
                const float* ob = obs + (size_t)tn * (BATCH * 2);
                #pragma unroll
                for (int r = 0; r < 4; ++r)
                    xn[r] = *(const f32x2*)&ob[(size_t)(rbw + q * 4 + r) * 2];
            }

            // gate init: x-contribution + bias (fp32)
            f32x4 acc[4];
            #pragma unroll
            for (int f = 0; f < 4; ++f)
                #pragma unroll
                for (int r = 0; r < 4; ++r)
                    acc[f][r] = fmaf(xc[r][1], w1v[f],
                               fmaf(xc[r][0], w0v[f], bcv[f]));

            // recurrent GEMM for this wave's 4 gate tiles (h==0 at t=0)
            if (t > 0) {
                const __bf16* hp = hlb[(t & 1) ^ 1];
                bf16x8 a0 = *(const bf16x8*)&hp[c16 * HSTR + q * 8];
                bf16x8 a1 = *(const bf16x8*)&hp[c16 * HSTR + 32 + q * 8];
                #pragma unroll
                for (int f = 0; f < 4; ++f) {
                    acc[f] = __builtin_amdgcn_mfma_f32_16x16x32_bf16(a0, bfr[f][0], acc[f], 0, 0, 0);
                    acc[f] = __builtin_amdgcn_mfma_f32_16x16x32_bf16(a1, bfr[f][1], acc[f], 0, 0, 0);
                }
            }

            // activations + state update for (rows q*4+r, hidden hOff)
            __bf16* hw = hlb[t & 1];
            #pragma unroll
            for (int r = 0; r < 4; ++r) {
                float ig = sigmoid_f(acc[0][r]);
                float fg = sigmoid_f(acc[1][r]);
                float gg = tanh_f(acc[2][r]);
                float og = sigmoid_f(acc[3][r]);
                float cc = fmaf(fg, cst[r], ig * gg);
                cst[r] = cc;
                float h = og * tanh_f(cc);
                if (t < T_STEPS - 1) {
                    hw[(q * 4 + r) * HSTR + hOff] = (__bf16)h;
                } else {
                    out[(size_t)(rbw + q * 4 + r) * HIDN + hOff] = h;
                }
            }

            __syncthreads();  // h quarters exchanged; also guards chunk reuse

            #pragma unroll
            for (int r = 0; r < 4; ++r) xc[r] = xn[r];
        }
    }
}

extern "C" void kernel_launch(void* const* d_in, const int* in_sizes, int n_in,
                              void* d_out, int out_size, void* d_ws, size_t ws_size,
                              hipStream_t stream) {
    const float* obs   = (const float*)d_in[0];
    const float* W_emb = (const float*)d_in[1];
    const float* b_emb = (const float*)d_in[2];
    const float* W_ih  = (const float*)d_in[3];
    const float* W_hh  = (const float*)d_in[4];
    const float* b_ih  = (const float*)d_in[5];
    const float* b_hh  = (const float*)d_in[6];
    float* out = (float*)d_out;

    dim3 grid(BATCH / (16 * CHUNKS));  // 2048 WGs = 8 per CU
    dim3 block(256);
    Encoder_6949257085628_kernel<<<grid, block, 0, stream>>>(
        obs, W_emb, b_emb, W_ih, W_hh, b_ih, b_hh, out);
}